// Round 16
// baseline (1758.433 us; speedup 1.0000x reference)
//
#include <hip/hip_runtime.h>
#include <cstdint>
#include <cstddef>

// GPT2-MLA forward, MI355X. Round 16: KV-split x2 flash attention (partial
// m/l/O + merge kernel) on top of the r12/r15 optimum. Everything else
// byte-identical to round 15.
// B=2,T=1024,D=768,L=12,H=12,HD=64,DL=256,V=50257 (wte padded to 50432=197*256)

typedef unsigned short ushortT;
typedef __bf16 bf16x8 __attribute__((ext_vector_type(8)));
typedef float f32x4 __attribute__((ext_vector_type(4)));

#define NHEAD 12
#define T_SEQ 1024

__device__ __forceinline__ float bf2f(unsigned short u) {
    union { unsigned int i; float f; } v; v.i = ((unsigned int)u) << 16; return v.f;
}
__device__ __forceinline__ unsigned short f2bf(float f) {
    union { float f; unsigned int i; } v; v.f = f;
    unsigned int r = v.i + 0x7fffu + ((v.i >> 16) & 1u);
    return (unsigned short)(r >> 16);
}
__device__ __forceinline__ unsigned int pack2(float a, float b) {
    return (unsigned int)f2bf(a) | ((unsigned int)f2bf(b) << 16);
}
__device__ __forceinline__ void gload_lds16(const void* g, void* l) {
    __builtin_amdgcn_global_load_lds((__attribute__((address_space(1))) void*)g,
                                     (__attribute__((address_space(3))) void*)l, 16, 0, 0);
}
template <int N>
__device__ __forceinline__ void wait_vmcnt() {
    if constexpr (N == 8)      asm volatile("s_waitcnt vmcnt(8)" ::: "memory");
    else if constexpr (N == 6) asm volatile("s_waitcnt vmcnt(6)" ::: "memory");
    else if constexpr (N == 5) asm volatile("s_waitcnt vmcnt(5)" ::: "memory");
    else if constexpr (N == 4) asm volatile("s_waitcnt vmcnt(4)" ::: "memory");
    else if constexpr (N == 3) asm volatile("s_waitcnt vmcnt(3)" ::: "memory");
    else                       asm volatile("s_waitcnt vmcnt(0)" ::: "memory");
}

// ---------------- weight convert / transpose (float4 / ushort4 vectorized) ----------------
__global__ __launch_bounds__(256) void transpose_cvt_kernel(
    const float* __restrict__ in, ushortT* __restrict__ outp,
    int K, int N, int outRowOff, size_t outLS) {
    __shared__ float tile[32][33];
    const int tid = threadIdx.x;
    const int n0 = blockIdx.x * 32, k0 = blockIdx.y * 32;
    const float* src = in + (size_t)blockIdx.z * K * N;
    {
        const int r = tid >> 3, cg = tid & 7;
        float4 v = *(const float4*)(src + (size_t)(k0 + r) * N + n0 + cg * 4);
        tile[r][cg * 4 + 0] = v.x; tile[r][cg * 4 + 1] = v.y;
        tile[r][cg * 4 + 2] = v.z; tile[r][cg * 4 + 3] = v.w;
    }
    __syncthreads();
    {
        const int nr = tid >> 3, kg = tid & 7;
        ushort4 o;
        o.x = f2bf(tile[kg * 4 + 0][nr]);
        o.y = f2bf(tile[kg * 4 + 1][nr]);
        o.z = f2bf(tile[kg * 4 + 2][nr]);
        o.w = f2bf(tile[kg * 4 + 3][nr]);
        ushortT* dst = outp + (size_t)blockIdx.z * outLS;
        *(ushort4*)(dst + (size_t)(outRowOff + n0 + nr) * K + k0 + kg * 4) = o;
    }
}

__global__ void cvt_wte_kernel(const float* __restrict__ in, ushortT* __restrict__ outp) {
    size_t i4 = (size_t)blockIdx.x * 256 + threadIdx.x;
    ushort4 o;
    if (i4 < 9649344) {
        float4 v = ((const float4*)in)[i4];
        o.x = f2bf(v.x); o.y = f2bf(v.y); o.z = f2bf(v.z); o.w = f2bf(v.w);
    } else { o.x = 0; o.y = 0; o.z = 0; o.w = 0; }
    ((ushort4*)outp)[i4] = o;
}

// ---------------- embedding ----------------
__global__ void embed_kernel(const int* __restrict__ idx, const float* __restrict__ wte,
                             const float* __restrict__ wpe, float* __restrict__ x) {
    int i = blockIdx.x * 256 + threadIdx.x;
    int row = i / 768, d = i - row * 768;
    int t = row & 1023;
    x[i] = wte[(size_t)idx[row] * 768 + d] + wpe[(size_t)t * 768 + d];
}

// ---------------- rope tables ----------------
__global__ void rope_tables_kernel(float* __restrict__ cosT, float* __restrict__ sinT) {
    int i = blockIdx.x * 256 + threadIdx.x;  // 1024*32
    int t = i >> 5, f = i & 31;
    float invf = exp2f(-(float)f * (13.287712379549449f / 32.0f));
    float ang = (float)t * invf;
    cosT[i] = cosf(ang);
    sinT[i] = sinf(ang);
}

// ---------------- layernorm (standalone; used once after embed) ----------------
__global__ __launch_bounds__(256) void ln_kernel(const float* __restrict__ x,
                                                 const float* __restrict__ wg,
                                                 const float* __restrict__ bg,
                                                 ushortT* __restrict__ outp) {
    const int row = blockIdx.x, tid = threadIdx.x;
    const float* xr = x + (size_t)row * 768;
    float v0 = xr[tid], v1 = xr[tid + 256], v2 = xr[tid + 512];
    float s = v0 + v1 + v2;
    float ss = v0 * v0 + v1 * v1 + v2 * v2;
#pragma unroll
    for (int off = 32; off >= 1; off >>= 1) {
        s += __shfl_xor(s, off);
        ss += __shfl_xor(ss, off);
    }
    __shared__ float sb[4], ssb[4];
    if ((tid & 63) == 0) { sb[tid >> 6] = s; ssb[tid >> 6] = ss; }
    __syncthreads();
    float S = sb[0] + sb[1] + sb[2] + sb[3];
    float SS = ssb[0] + ssb[1] + ssb[2] + ssb[3];
    const float mean = S * (1.0f / 768.0f);
    float var = SS * (1.0f / 768.0f) - mean * mean;
    const float rs = rsqrtf(var + 1e-5f);
    ushortT* orow = outp + (size_t)row * 768;
    orow[tid]       = f2bf((v0 - mean) * rs * wg[tid]       + bg[tid]);
    orow[tid + 256] = f2bf((v1 - mean) * rs * wg[tid + 256] + bg[tid + 256]);
    orow[tid + 512] = f2bf((v2 - mean) * rs * wg[tid + 512] + bg[tid + 512]);
}

// ---------------- fused split-K reduce + residual + LayerNorm ----------------
template <int NP>
__global__ __launch_bounds__(256) void reduce_ln_kernel(
    float* __restrict__ x, const float* __restrict__ part,
    const float* __restrict__ bias,
    const float* __restrict__ wg, const float* __restrict__ bg,
    ushortT* __restrict__ outp) {
    const int row = blockIdx.x, tid = threadIdx.x;
    const size_t base = (size_t)row * 768;
    float4 v = {0.f, 0.f, 0.f, 0.f};
    if (tid < 192) {
        v = *(const float4*)(x + base + tid * 4);
        const float4 b4 = *(const float4*)(bias + tid * 4);
        v.x += b4.x; v.y += b4.y; v.z += b4.z; v.w += b4.w;
#pragma unroll
        for (int p = 0; p < NP; ++p) {
            const float4 pv = *(const float4*)(part + (size_t)p * 1572864 + base + tid * 4);
            v.x += pv.x; v.y += pv.y; v.z += pv.z; v.w += pv.w;
        }
        *(float4*)(x + base + tid * 4) = v;
    }
    float s = v.x + v.y + v.z + v.w;
    float ss = v.x * v.x + v.y * v.y + v.z * v.z + v.w * v.w;
#pragma unroll
    for (int off = 32; off >= 1; off >>= 1) {
        s += __shfl_xor(s, off);
        ss += __shfl_xor(ss, off);
    }
    __shared__ float sb[4], ssb[4];
    if ((tid & 63) == 0) { sb[tid >> 6] = s; ssb[tid >> 6] = ss; }
    __syncthreads();
    const float S = sb[0] + sb[1] + sb[2] + sb[3];
    const float SS = ssb[0] + ssb[1] + ssb[2] + ssb[3];
    const float mean = S * (1.0f / 768.0f);
    const float var = SS * (1.0f / 768.0f) - mean * mean;
    const float rs = rsqrtf(var + 1e-5f);
    if (tid < 192) {
        const float4 w4 = *(const float4*)(wg + tid * 4);
        const float4 g4 = *(const float4*)(bg + tid * 4);
        ushort4 o;
        o.x = f2bf((v.x - mean) * rs * w4.x + g4.x);
        o.y = f2bf((v.y - mean) * rs * w4.y + g4.y);
        o.z = f2bf((v.z - mean) * rs * w4.z + g4.z);
        o.w = f2bf((v.w - mean) * rs * w4.w + g4.w);
        *(ushort4*)(outp + base + tid * 4) = o;
    }
}

// ---------------- generic GEMM (r8 skeleton) ----------------
template <int BM, int NF, int NTHR, bool ROPE, bool PARTIAL = false>
__global__ __launch_bounds__(NTHR) void gemmT(
    const ushortT* __restrict__ A, int lda,
    const ushortT* __restrict__ Bt, int ldb,
    int K, int CS, int Nstore,
    const float* __restrict__ bias0, const float* __restrict__ bias1,
    ushortT* __restrict__ outB0, int ld0,
    ushortT* __restrict__ outB1, int ld1, int mode1,
    const float* __restrict__ resid, float* __restrict__ outF, int ldF,
    int act, const float* __restrict__ cosT, const float* __restrict__ sinT) {
    constexpr int WC = (NTHR == 512) ? 4 : 2;
    constexpr int WMR = BM / 2;
    constexpr int MF = WMR / 16;
    constexpr int NFh = NF / WC;
    constexpr int WNh = NFh * 16;
    constexpr int ABYTES = BM * 128;
    constexpr int BBYTES = NF * 2048;
    constexpr int BUFB = ABYTES + BBYTES;
    constexpr int A_LOADS = (BM * 8) / NTHR;
    constexpr int B_LOADS = (NF * 128) / NTHR;
    constexpr int S = A_LOADS + B_LOADS;
    __shared__ __align__(16) char lds[2 * BUFB];
    const int tid = threadIdx.x;
    const int w = tid >> 6, lane = tid & 63;
    const int wm = w / WC, wn = w % WC;
    const int gx = gridDim.x;
    const int nwg = gx * gridDim.y;
    const int flat = blockIdx.x + gx * blockIdx.y;
    const int xcd = flat & 7, loc = flat >> 3;
    const int qq = nwg >> 3, rr_ = nwg & 7;
    const int swz = (xcd < rr_ ? xcd * (qq + 1) : rr_ * (qq + 1) + (xcd - rr_) * qq) + loc;
    const int m0 = (swz % gx) * BM, n0 = (swz / gx) * NF * 16;
    const int fr = lane & 15, kg = lane >> 4;
    const size_t ldaB = (size_t)lda * 2, ldbB = (size_t)ldb * 2;
    int koff = 0;
    if constexpr (PARTIAL) koff = blockIdx.z * K;
    const char* Ab = (const char*)A + (size_t)koff * 2;
    const char* Bb = (const char*)Bt + (size_t)koff * 2;
    float* outFz = outF;
    if constexpr (PARTIAL) outFz = outF + (size_t)blockIdx.z * 2048 * (size_t)ldF;
    f32x4 acc[MF][NFh] = {};

    auto stage = [&](int buf, int t) {
        const size_t ktB = (size_t)t << 7;
        char* As_ = lds + buf * BUFB;
        char* Bs_ = As_ + ABYTES;
#pragma unroll
        for (int jj = 0; jj < A_LOADS; ++jj) {
            const int i = tid + jj * NTHR;
            const int r = i >> 3, c = i & 7, cc = c ^ (r & 7);
            gload_lds16(Ab + (size_t)(m0 + r) * ldaB + ktB + cc * 16, As_ + i * 16);
        }
#pragma unroll
        for (int jj = 0; jj < B_LOADS; ++jj) {
            const int i = tid + jj * NTHR;
            const int r = i >> 3, c = i & 7, cc = c ^ (r & 7);
            gload_lds16(Bb + (size_t)(n0 + r) * ldbB + ktB + cc * 16, Bs_ + i * 16);
        }
    };

    const int nk = K >> 6;
    stage(0, 0);
    if (nk > 1) { stage(1, 1); wait_vmcnt<S>(); }
    else        { wait_vmcnt<0>(); }
    __builtin_amdgcn_s_barrier();

    for (int t = 0; t < nk; ++t) {
        const int cur = t & 1;
        const char* As_ = lds + cur * BUFB;
        const char* Bs_ = As_ + ABYTES;
        bf16x8 af[MF][2], bfr[NFh][2];
#pragma unroll
        for (int mf = 0; mf < MF; ++mf) {
            const int row = wm * WMR + mf * 16 + fr;
#pragma unroll
            for (int ks = 0; ks < 2; ++ks)
                af[mf][ks] = *(const bf16x8*)(As_ + row * 128 + (((ks * 4 + kg) ^ (row & 7)) << 4));
        }
#pragma unroll
        for (int nf = 0; nf < NFh; ++nf) {
            const int row = wn * WNh + nf * 16 + fr;
#pragma unroll
            for (int ks = 0; ks < 2; ++ks)
                bfr[nf][ks] = *(const bf16x8*)(Bs_ + row * 128 + (((ks * 4 + kg) ^ (row & 7)) << 4));
        }
        if (t + 2 < nk) {
            asm volatile("s_waitcnt lgkmcnt(0)" ::: "memory");
            __builtin_amdgcn_s_barrier();
            stage(cur, t + 2);
        }
#pragma unroll
        for (int ks = 0; ks < 2; ++ks)
#pragma unroll
            for (int nf = 0; nf < NFh; ++nf)
#pragma unroll
                for (int mf = 0; mf < MF; ++mf)
                    acc[mf][nf] = __builtin_amdgcn_mfma_f32_16x16x32_bf16(
                        af[mf][ks], bfr[nf][ks], acc[mf][nf], 0, 0, 0);
        if (t + 1 < nk) {
            if (t + 2 < nk) wait_vmcnt<S>();
            else            wait_vmcnt<0>();
            __builtin_amdgcn_s_barrier();
        }
    }

    if constexpr (ROPE) {
        float vv[MF][4][4];
#pragma unroll
        for (int mf = 0; mf < MF; ++mf)
#pragma unroll
            for (int nf = 0; nf < 4; ++nf) {
                const int gcol = n0 + wn * 64 + nf * 16 + fr;
                float bv = (gcol < CS) ? (bias0 ? bias0[gcol] : 0.0f)
                                       : (bias1 ? bias1[gcol - CS] : 0.0f);
#pragma unroll
                for (int j = 0; j < 4; ++j) vv[mf][nf][j] = acc[mf][nf][j] + bv;
            }
        if (n0 + wn * 64 < 768) {
#pragma unroll
            for (int mf = 0; mf < MF; ++mf)
#pragma unroll
                for (int j = 0; j < 4; ++j) {
                    const int grow = m0 + wm * WMR + mf * 16 + kg * 4 + j;
                    const int t = grow & 1023;
                    const float c0 = cosT[t * 32 + fr],      s0 = sinT[t * 32 + fr];
                    const float c1 = cosT[t * 32 + 16 + fr], s1 = sinT[t * 32 + 16 + fr];
                    float x1 = vv[mf][0][j], x2 = vv[mf][2][j];
                    vv[mf][0][j] = x1 * c0 - x2 * s0;
                    vv[mf][2][j] = x2 * c0 + x1 * s0;
                    float y1 = vv[mf][1][j], y2 = vv[mf][3][j];
                    vv[mf][1][j] = y1 * c1 - y2 * s1;
                    vv[mf][3][j] = y2 * c1 + y1 * s1;
                }
        }
#pragma unroll
        for (int mf = 0; mf < MF; ++mf)
#pragma unroll
            for (int nf = 0; nf < 4; ++nf) {
                const int gcol = n0 + wn * 64 + nf * 16 + fr;
                if (gcol >= Nstore) continue;
#pragma unroll
                for (int j = 0; j < 4; ++j) {
                    const int grow = m0 + wm * WMR + mf * 16 + kg * 4 + j;
                    const float v = vv[mf][nf][j];
                    if (gcol < CS) {
                        if (outB0) outB0[(size_t)grow * ld0 + gcol] = f2bf(v);
                    } else if (outB1) {
                        if (mode1 == 0) {
                            outB1[(size_t)grow * ld1 + gcol - CS] = f2bf(v);
                        } else {
                            const int bb = grow >> 10, tt = grow & 1023;
                            const int hd = gcol - CS;
                            outB1[((size_t)((bb * 12 + (hd >> 6)) * 64 + (hd & 63)) << 10) + tt] = f2bf(v);
                        }
                    }
                }
            }
    } else {
#pragma unroll
        for (int mf = 0; mf < MF; ++mf) {
#pragma unroll
            for (int nf = 0; nf < NFh; ++nf) {
                const int gcol = n0 + wn * WNh + nf * 16 + fr;
                if (gcol >= Nstore) continue;
                float bv = 0.0f;
                if (gcol < CS) { if (bias0) bv = bias0[gcol]; }
                else           { if (bias1) bv = bias1[gcol - CS]; }
#pragma unroll
                for (int j = 0; j < 4; ++j) {
                    const int grow = m0 + wm * WMR + mf * 16 + kg * 4 + j;
                    float v = acc[mf][nf][j] + bv;
                    if (resid) v += resid[(size_t)grow * ldF + gcol];
                    if (act) v = 0.5f * v * (1.0f + erff(v * 0.70710678118654752f));
                    if (outFz) outFz[(size_t)grow * ldF + gcol] = v;
                    if (gcol < CS) {
                        if (outB0) outB0[(size_t)grow * ld0 + gcol] = f2bf(v);
                    } else if (outB1) {
                        if (mode1 == 0) {
                            outB1[(size_t)grow * ld1 + gcol - CS] = f2bf(v);
                        } else {
                            const int bb = grow >> 10, tt = grow & 1023;
                            const int hd = gcol - CS;
                            outB1[((size_t)((bb * 12 + (hd >> 6)) * 64 + (hd & 63)) << 10) + tt] = f2bf(v);
                        }
                    }
                }
            }
        }
    }
}

// ---------------- 4-phase 128x(NFW*64) GEMM (fc / proj), K = 768 per slice ----
#define FC_PHASE(SLOT, MB, STAGE_STMT, TAILWAIT)                               \
    {                                                                          \
        bf16x8 af[2][2];                                                       \
        _Pragma("unroll") for (int m = 0; m < 2; ++m)                          \
        _Pragma("unroll") for (int ks = 0; ks < 2; ++ks) {                     \
            const int row = wm * 64 + (MB + m) * 16 + fr;                      \
            af[m][ks] = *(const bf16x8*)(lds + (SLOT) * 16384 + row * 128 +    \
                                         (((ks * 4 + kg) ^ (row & 7)) << 4));  \
        }                                                                      \
        STAGE_STMT;                                                            \
        __builtin_amdgcn_s_barrier();                                          \
        asm volatile("s_waitcnt lgkmcnt(0)" ::: "memory");                     \
        __builtin_amdgcn_sched_barrier(0);                                     \
        __builtin_amdgcn_s_setprio(1);                                         \
        _Pragma("unroll") for (int ks = 0; ks < 2; ++ks)                       \
        _Pragma("unroll") for (int nf = 0; nf < NFW; ++nf)                     \
        _Pragma("unroll") for (int m = 0; m < 2; ++m)                          \
            acc[MB + m][nf] = __builtin_amdgcn_mfma_f32_16x16x32_bf16(         \
                af[m][ks], bfr[nf][ks], acc[MB + m][nf], 0, 0, 0);             \
        __builtin_amdgcn_s_setprio(0);                                         \
        TAILWAIT;                                                              \
        __builtin_amdgcn_s_barrier();                                          \
    }

template <int NFW, bool GELU, bool PARTIAL>
__global__ __launch_bounds__(512, 1) void gemm8(
    const ushortT* __restrict__ A, int lda,
    const ushortT* __restrict__ Bt, int ldb,
    const float* __restrict__ bias,
    ushortT* __restrict__ outB, int ldo,
    float* __restrict__ outF) {
    constexpr int BSLOT = NFW * 8192;           // B bytes per slot
    __shared__ __align__(16) char lds[32768 + 2 * BSLOT];
    const int tid = threadIdx.x;
    const int w = tid >> 6, lane = tid & 63;
    const int wm = w >> 2, wn = w & 3;          // 2M x 4N waves
    const int fr = lane & 15, kg = lane >> 4;
    const int gx = gridDim.x;
    const int nwg = gx * gridDim.y;             // multiple of 8 for all users
    const int flat = blockIdx.x + gx * blockIdx.y;
    const int cpx = nwg >> 3;
    const int swz = (flat & 7) * cpx + (flat >> 3);
    const int m0 = (swz % gx) * 128, n0 = (swz / gx) * (NFW * 64);
    const size_t ldaB = (size_t)lda * 2, ldbB = (size_t)ldb * 2;
    int koff = 0;
    if constexpr (PARTIAL) koff = blockIdx.z * 768;
    const char* Ag = (const char*)A + (size_t)koff * 2;
    const char* Bg = (const char*)Bt + (size_t)koff * 2;
    float* outFz = nullptr;
    if constexpr (PARTIAL) outFz = outF + (size_t)blockIdx.z * 2048 * 768;

    auto stA = [&](int tile) {  // 2 loads/thread
        char* dst = lds + (tile & 1) * 16384;
#pragma unroll
        for (int jj = 0; jj < 2; ++jj) {
            const int i = tid + jj * 512;
            const int r = i >> 3, c = i & 7, cc = c ^ (r & 7);
            gload_lds16(Ag + (size_t)(m0 + r) * ldaB + tile * 128 + cc * 16, dst + i * 16);
        }
    };
    auto stB = [&](int tile) {  // NFW loads/thread
        char* dst = lds + 32768 + (tile & 1) * BSLOT;
#pragma unroll
        for (int jj = 0; jj < NFW; ++jj) {
            const int i = tid + jj * 512;
            const int r = i >> 3, c = i & 7, cc = c ^ (r & 7);
            gload_lds16(Bg + (size_t)(n0 + r) * ldbB + tile * 128 + cc * 16, dst + i * 16);
        }
    };

    f32x4 acc[4][NFW] = {};
    // prologue: A(0), B(0), B(1); wait leaves B(1)'s NFW loads in flight
    stA(0); stB(0); stB(1);
    wait_vmcnt<NFW>();
    __builtin_amdgcn_s_barrier();

    const int browB = wn * (NFW * 16);
    for (int i = 0; i < 6; ++i) {  // 12 K-tiles of 64, 2 per iter
        const int t1 = 2 * i + 1;
        const bool st = (i < 5);
        bf16x8 bfr[NFW][2];
#pragma unroll
        for (int nf = 0; nf < NFW; ++nf)
#pragma unroll
            for (int ks = 0; ks < 2; ++ks) {
                const int row = browB + nf * 16 + fr;
                bfr[nf][ks] = *(const bf16x8*)(lds + 32768 + 0 * BSLOT + row * 128 +
                                               (((ks * 4 + kg) ^ (row & 7)) << 4));
            }
        FC_PHASE(0, 0, stA(t1), )
        FC_PHASE(0, 2, if (st) stB(t1 + 1),
                 if (st) { wait_vmcnt<NFW>(); } else { wait_vmcnt<0>(); }
                 __builtin_amdgcn_sched_barrier(0))
#pragma unroll
        for (int nf = 0; nf < NFW; ++nf)
#pragma unroll
            for (int ks = 0; ks < 2; ++ks) {
                const int row = browB + nf * 16 + fr;
                bfr[nf][ks] = *(const bf16x8*)(lds + 32768 + 1 * BSLOT + row * 128 +
                                               (((ks * 4 + kg) ^ (row & 7)) << 4));
            }
        FC_PHASE(1, 0, if (st) stA(t1 + 1), )
        FC_PHASE(1, 2, if (st) stB(t1 + 2),
                 if (st) { wait_vmcnt<NFW>(); } else { wait_vmcnt<0>(); }
                 __builtin_amdgcn_sched_barrier(0))
    }

    // epilogue
#pragma unroll
    for (int mf = 0; mf < 4; ++mf)
#pragma unroll
        for (int nf = 0; nf < NFW; ++nf) {
            const int col = n0 + wn * (NFW * 16) + nf * 16 + fr;
#pragma unroll
            for (int j = 0; j < 4; ++j) {
                const int row = m0 + wm * 64 + mf * 16 + kg * 4 + j;
                if constexpr (PARTIAL) {
                    outFz[(size_t)row * 768 + col] = acc[mf][nf][j];
                } else {
                    float v = acc[mf][nf][j] + bias[col];
                    if constexpr (GELU)
                        v = 0.5f * v * (1.0f + erff(v * 0.70710678118654752f));
                    outB[(size_t)row * ldo + col] = f2bf(v);
                }
            }
        }
}

// ---------------- 8-phase 256x256 lm_head ----------
#define LM_PHASE(SLOT, MB, STAGE_STMT, TAILWAIT)                              \
    {                                                                          \
        bf16x8 af[2][2];                                                       \
        _Pragma("unroll") for (int m = 0; m < 2; ++m)                          \
        _Pragma("unroll") for (int ks = 0; ks < 2; ++ks) {                     \
            const int row = (MB + m) * 16 + fr;                                \
            af[m][ks] = *(const bf16x8*)(Aw + (SLOT) * 32768 + row * 128 +     \
                                         (((ks * 4 + kg) ^ (row & 7)) << 4));  \
        }                                                                      \
        STAGE_STMT;                                                            \
        __builtin_amdgcn_s_barrier();                                          \
        asm volatile("s_waitcnt lgkmcnt(0)" ::: "memory");                     \
        __builtin_amdgcn_sched_barrier(0);                                     \
        __builtin_amdgcn_s_setprio(1);                                         \
        _Pragma("unroll") for (int ks = 0; ks < 2; ++ks)                       \
        _Pragma("unroll") for (int nf = 0; nf < 4; ++nf)                       \
        _Pragma("unroll") for (int m = 0; m < 2; ++m)                          \
            acc[MB + m][nf] = __builtin_amdgcn_mfma_f32_16x16x32_bf16(         \
                af[m][ks], bfr[nf][ks], acc[MB + m][nf], 0, 0, 0);             \
        __builtin_amdgcn_s_setprio(0);                                         \
        TAILWAIT;                                                              \
        __builtin_amdgcn_s_barrier();                                          \
    }

__global__ __launch_bounds__(512, 1) void lmhead8(
    const ushortT* __restrict__ A, const ushortT* __restrict__ Bt,
    float* __restrict__ outF) {
    __shared__ __align__(16) char lds[131072];
    const int tid = threadIdx.x;
    const int w = tid >> 6, lane = tid & 63;
    const int wm = w >> 2, wn = w & 3;
    const int fr = lane & 15, kg = lane >> 4;
    const int flat = blockIdx.x + 8 * blockIdx.y;
    const int swz = (flat & 7) * 197 + (flat >> 3);
    const int m0 = (swz & 7) * 256, n0 = (swz >> 3) * 256;

    const char* Ag = (const char*)A;
    const char* Bg = (const char*)Bt;
    const char* Aw = lds + wm * 16384;
    const char* Bw = lds + 65536 + (wn >> 1) * 16384;
    const int brow0 = (wn & 1) * 64;

    auto stA = [&](int tile, int half) {
        char* dst = lds + (tile & 1) * 32768 + half * 16384;
#pragma unroll
        for (int jj = 0; jj < 2; ++jj) {
            const int i = tid + jj * 512;
            const int r = i >> 3, c = i & 7, cc = c ^ (r & 7);
            gload_lds16(Ag + (size_t)(m0 + half * 128 + r) * 1536 + tile * 128 + cc * 16,
                        dst + i * 16);
        }
    };
    auto stB = [&](int tile, int half) {
        char* dst = lds + 65536 + (tile & 1) * 32768 + half * 16384;
#pragma unroll
        for (int jj = 0; jj < 2; ++jj) {
            const int i = tid + jj * 512;
            const int r = i >> 3, c = i & 7, cc = c ^ (r & 7);
            gload_lds16(Bg + (size_t)(n0 + half * 128 + r) * 1536 + tile * 128 + cc * 16,
                        dst + i * 16);
        }
    };

    f32x4 acc[8][4] = {};
    stA(0, 0); stA(0, 1); stB(0, 0); stB(0, 1); stB(1, 0); stB(1, 1);
    wait_vmcnt<4>();
    __builtin_amdgcn_s_barrier();

    for (int i = 0; i < 6; ++i) {
        const int t1 = 2 * i + 1;
        const bool st = (i < 5);
        bf16x8 bfr[4][2];
#pragma unroll
        for (int nf = 0; nf < 4; ++nf)
#pragma unroll
            for (int ks = 0; ks < 2; ++ks) {
                const int row = brow0 + nf * 16 + fr;
                bfr[nf][ks] = *(const bf16x8*)(Bw + 0 * 32768 + row * 128 +
                                               (((ks * 4 + kg) ^ (row & 7)) << 4));
            }
        LM_PHASE(0, 0, stA(t1, 0), )
        LM_PHASE(0, 2, stA(t1, 1), )
        LM_PHASE(0, 4, if (st) stB(t1 + 1, 0), )
        LM_PHASE(0, 6, if (st) stB(t1 + 1, 1),
                 if (st) { wait_vmcnt<4>(); } else { wait_vmcnt<0>(); }
                 __builtin_amdgcn_sched_barrier(0))
#pragma unroll
        for (int nf = 0; nf < 4; ++nf)
#pragma unroll
            for (int ks = 0; ks < 2; ++ks) {
                const int row = brow0 + nf * 16 + fr;
                bfr[nf][ks] = *(const bf16x8*)(Bw + 1 * 32768 + row * 128 +
                                               (((ks * 4 + kg) ^ (row & 7)) << 4));
            }
        LM_PHASE(1, 0, if (st) stA(t1 + 1, 0), )
        LM_PHASE(1, 2, if (st) stA(t1 + 1, 1), )
        LM_PHASE(1, 4, if (st) stB(t1 + 2, 0), )
        LM_PHASE(1, 6, if (st) stB(t1 + 2, 1),
                 if (st) { wait_vmcnt<4>(); } else { wait_vmcnt<0>(); }
                 __builtin_amdgcn_sched_barrier(0))
    }

#pragma unroll
    for (int mf = 0; mf < 8; ++mf)
#pragma unroll
        for (int nf = 0; nf < 4; ++nf) {
            const int col = n0 + wn * 64 + nf * 16 + fr;
            if (col < 50257) {
#pragma unroll
                for (int j = 0; j < 4; ++j) {
                    const int row = m0 + wm * 128 + mf * 16 + kg * 4 + j;
                    outF[(size_t)row * 50257 + col] = acc[mf][nf][j];
                }
            }
        }
}

// ---------------- MFMA flash attention, KV-split x2 (partial m/l/O) ----------
// grid (16, 24, 2): z selects KV half. z=0 tiles [0,h0), z=1 tiles [h0,nst).
// Partials: oP[z][2048][768] f32 (unnormalized), mlb[z][bh][t] = {m, l}.
__global__ __launch_bounds__(256) void attn_mfma(const ushortT* __restrict__ q,
                                                 const ushortT* __restrict__ kbuf,
                                                 const ushortT* __restrict__ vT,
                                                 float* __restrict__ oP,
                                                 float2* __restrict__ mlb) {
    __shared__ __align__(16) char lds[41472];
    const int tid = threadIdx.x, w = tid >> 6, lane = tid & 63;
    const int fr = lane & 15, kg = lane >> 4;
    const int flat = blockIdx.x + 16 * blockIdx.y;
    const int z = blockIdx.z;
    const int nf2 = (flat & 7) * 48 + (flat >> 3);
    const int bh = nf2 >> 4;
    const int b = bh / NHEAD, h = bh % NHEAD;
    const int qb = (15 - (nf2 & 15)) * 64;
    const int q0 = qb + w * 16;
    const int nst = (qb >> 6) + 1, diag = qb >> 6;
    const int h0 = (nst + 1) >> 1;
    const int st0 = z ? h0 : 0, st1 = z ? nst : h0;
    const int cnt = st1 - st0;

    const ushortT* qrow = q + ((size_t)(b * 1024 + q0 + fr) * 768 + h * 64);
    const bf16x8 qf0 = *(const bf16x8*)(qrow + kg * 8);
    const bf16x8 qf1 = *(const bf16x8*)(qrow + 32 + kg * 8);

    const char* kgb = (const char*)kbuf + ((size_t)(b * 1024) * 768 + h * 64) * 2;
    const char* vgb = (const char*)vT + ((size_t)(b * 12 + h) * 65536) * 2;
    char* Pw = lds + 32768 + w * 2176 + fr * 136;

    auto stage = [&](int buf, int st) {
#pragma unroll
        for (int jj = 0; jj < 2; ++jj) {
            const int i = tid + jj * 256;
            const int r = i >> 3, c = i & 7, cc = c ^ (r & 7);
            gload_lds16(kgb + (size_t)(st * 64 + r) * 1536 + cc * 16, lds + buf * 8192 + i * 16);
            gload_lds16(vgb + (size_t)r * 2048 + st * 128 + cc * 16, lds + 16384 + buf * 8192 + i * 16);
        }
    };

    float m_r = -1e30f, l_r = 0.0f;
    f32x4 o[4] = {};

    if (cnt > 0) stage(0, st0);
    if (cnt > 1) stage(1, st0 + 1);
    for (int st = st0; st < st1; ++st) {
        const int cur = (st - st0) & 1;
        if (st + 1 < st1) wait_vmcnt<4>();
        else              wait_vmcnt<0>();
        __builtin_amdgcn_s_barrier();
        const char* Kd = lds + cur * 8192;
        const char* Vd = lds + 16384 + cur * 8192;

        f32x4 sfr[4];
        __builtin_amdgcn_s_setprio(1);
#pragma unroll
        for (int n = 0; n < 4; ++n) {
            const int row = n * 16 + fr;
            bf16x8 k0 = *(const bf16x8*)(Kd + row * 128 + ((kg ^ (row & 7)) << 4));
            bf16x8 k1 = *(const bf16x8*)(Kd + row * 128 + (((4 + kg) ^ (row & 7)) << 4));
            f32x4 sa = {0.0f, 0.0f, 0.0f, 0.0f};
            sa = __builtin_amdgcn_mfma_f32_16x16x32_bf16(k0, qf0, sa, 0, 0, 0);
            sa = __builtin_amdgcn_mfma_f32_16x16x32_bf16(k1, qf1, sa, 0, 0, 0);
            sfr[n] = sa;
        }
        __builtin_amdgcn_s_setprio(0);
        const int qoff = w * 16 + fr;
#pragma unroll
        for (int n = 0; n < 4; ++n)
#pragma unroll
            for (int j = 0; j < 4; ++j) {
                float v = sfr[n][j] * 0.125f;
                if (st == diag && (n * 16 + kg * 4 + j) > qoff) v = -1e30f;
                sfr[n][j] = v;
            }
        float tm = -1e30f;
#pragma unroll
        for (int n = 0; n < 4; ++n)
#pragma unroll
            for (int j = 0; j < 4; ++j) tm = fmaxf(tm, sfr[n][j]);
        tm = fmaxf(tm, __shfl_xor(tm, 16));
        tm = fmaxf(tm, __shfl_xor(tm, 32));
        // defer-max (T13): keep old running max when growth <= 8; P bounded by e^8
        if (!__all(tm <= m_r + 8.0f)) {
            const float mnew = fmaxf(m_r, tm);
            const float fac = __expf(m_r - mnew);
            m_r = mnew;
            l_r *= fac;
            const float ff0 = __shfl(fac, kg * 4 + 0);
            const float ff1 = __shfl(fac, kg * 4 + 1);
            const float ff2 = __shfl(fac, kg * 4 + 2);
            const float ff3 = __shfl(fac, kg * 4 + 3);
#pragma unroll
            for (int nf = 0; nf < 4; ++nf) {
                o[nf][0] *= ff0; o[nf][1] *= ff1; o[nf][2] *= ff2; o[nf][3] *= ff3;
            }
        }
#pragma unroll
        for (int n = 0; n < 4; ++n) {
            float e0 = __expf(sfr[n][0] - m_r);
            float e1 = __expf(sfr[n][1] - m_r);
            float e2 = __expf(sfr[n][2] - m_r);
            float e3 = __expf(sfr[n][3] - m_r);
            l_r += (e0 + e1) + (e2 + e3);
            uint2 pv;
            pv.x = pack2(e0, e1);
            pv.y = pack2(e2, e3);
            *(uint2*)(Pw + n * 32 + kg * 8) = pv;
        }
        __builtin_amdgcn_s_setprio(1);
#pragma unroll
        for (int ks = 0; ks < 2; ++ks) {
            uint2 a0 = *(const uint2*)(Pw + ks * 64 + kg * 16);
            uint2 a1 = *(const uint2*)(Pw + ks * 64 + kg * 16 + 8);
            union { uint4 u; bf16x8 v; } pa;
            pa.u = make_uint4(a0.x, a0.y, a1.x, a1.y);
#pragma unroll
            for (int nf = 0; nf < 4; ++nf) {
                const int row = nf * 16 + fr;
                bf16x8 vf = *(const bf16x8*)(Vd + row * 128 + (((ks * 4 + kg) ^ (row & 7)) << 4));
                o[nf] = __builtin_amdgcn_mfma_f32_16x16x32_bf16(pa.v, vf, o[nf], 0, 0, 0);
            }
        }
        __builtin_amdgcn_s_setprio(0);
        __builtin_amdgcn_s_barrier();
        if (st + 2 < st1) stage(cur, st + 2);
    }

    // row-sum of l (lanes with same fr), then write UNNORMALIZED partials
    l_r += __shfl_xor(l_r, 16);
    l_r += __shfl_xor(l_r, 32);
    float* oPz = oP + (size_t)z * 1572864;
#pragma unroll
    for (int nf = 0; nf < 4; ++nf) {
        const size_t base = (size_t)(b * 1024 + q0) * 768 + h * 64 + nf * 16 + fr;
        oPz[base + (size_t)(kg * 4 + 0) * 768] = o[nf][0];
        oPz[base + (size_t)(kg * 4 + 1) * 768] = o[nf][1];
        oPz[base + (size_t)(kg * 4 + 2) * 768] = o[nf][2];
        oPz[base + (size_t)(kg * 4 + 3) * 768] = o[nf][3];
    }
    if (lane < 16) {  // kg==0 lane holds row fr's m,l (row-uniform)
        float2 ml; ml.x = m_r; ml.y = l_r;
        mlb[((size_t)z * 24 + bh) * 1024 + (q0 + fr)] = ml;
    }
}

// ---------------- attention partial merge ----------------
// attnb[row][col] = (o0*w0 + o1*w1) / (l0*w0 + l1*w1), w_z = exp(m_z - max m)
__global__ __launch_bounds__(256) void attn_merge(const float* __restrict__ oP,
                                                  const float2* __restrict__ mlb,
                                                  ushortT* __restrict__ attnb) {
    const int row = blockIdx.x, tid = threadIdx.x;  // 2048 rows
    const int b = row >> 10, t = row & 1023;
    const size_t base = (size_t)row * 768;
#pragma unroll
    for (int k = 0; k < 3; ++k) {
        const int col = tid + k * 256;
        const int h = col >> 6;
        const float2 ml0 = mlb[((size_t)0 * 24 + b * 12 + h) * 1024 + t];
        const float2 ml1 = mlb[((size_t)1 * 24 + b * 12 + h) * 1024 + t];
        const float m = fmaxf(ml0.x, ml1.x);
        const float w0 = __expf(ml0.x - m), w1 = __expf(ml1.x - m);
        const float L = ml0.y * w0 + ml1.y * w1;
        const float v = (oP[base + col] * w0 + oP[1572864 + base + col] * w1) / L;
        attnb[base + col] = f2bf(v);
    }
}

// ---------------- host ----------------
extern "C" void kernel_launch(void* const* d_in, const int* in_sizes, int n_in,
                              void* d_out, int out_size, void* d_ws, size_t ws_size,
                              hipStream_t stream) {
    (void)in_sizes; (void)n_in; (void)out_size; (void)ws_size;
    const int*   idxp   = (const int*)d_in[0];
    const float* wte    = (const float*)d_in[1];
    const float* wpe    = (const float*)d_in[2];
    const float* ln1_w  = (const float*)d_in[3];
    const float* ln1_b  = (const float*)d_in[4];
    const float* wq_w   = (const float*)d_in[5];
    const float* wq_b   = (const float*)d_in[6];
    const float* kva_w  = (const float*)d_in[7];
    const float* kva_b  = (const float*)d_in[8];
    const float* kvb_w  = (const float*)d_in[9];
    const float* kvb_b  = (const float*)d_in[10];
    const float* out_w  = (const float*)d_in[11];
    const float* out_b  = (const float*)d_in[12];
    const float* ln2_w  = (const float*)d_in[13];
    const float* ln2_b  = (const float*)d_in[14];
    const float* fc_w   = (const float*)d_in[15];
    const float* fc_b   = (const float*)d_in[16];
    const float* proj_w = (const float*)d_in[17];
    const float* proj_b = (const float*)d_in[18];
    const float* lnf_w  = (const float*)d_in[19];
    const float* lnf_b  = (const float*)d_in[20];

    char* ws = (char*)d_ws;
    size_t off = 0;
    auto alloc = [&](size_t bytes) -> char* {
        char* p = ws + off;
        off += (bytes + 255) & ~(size_t)255;
        return p;
    };
    ushortT* wqkvaT = (ushortT*)alloc((size_t)12 * 1024 * 768 * 2);
    ushortT* kvbT   = (ushortT*)alloc((size_t)12 * 1536 * 256 * 2);
    ushortT* outT   = (ushortT*)alloc((size_t)12 * 768 * 768 * 2);
    ushortT* fcT    = (ushortT*)alloc((size_t)12 * 3072 * 768 * 2);
    ushortT* projT  = (ushortT*)alloc((size_t)12 * 768 * 3072 * 2);
    ushortT* wteB   = (ushortT*)alloc((size_t)50432 * 768 * 2);
    float* cosT = (float*)alloc((size_t)1024 * 32 * 4);
    float* sinT = (float*)alloc((size_t)1024 * 32 * 4);
    float*   x     = (float*)alloc((size_t)2048 * 768 * 4);
    ushortT* h     = (ushortT*)alloc((size_t)2048 * 768 * 2);
    ushortT* qbuf  = (ushortT*)alloc((size_t)2048 * 768 * 2);
    ushortT* lat   = (ushortT*)alloc((size_t)2048 * 256 * 2);
    ushortT* kvbuf = (ushortT*)alloc((size_t)2048 * 768 * 2);
    ushortT* vTb   = (ushortT*)alloc((size_t)24 * 64 * 1024 * 2);
    ushortT* attnb = (ushortT*)alloc((size_t)2048 * 768 * 2);
    ushortT* fca   = (ushortT*)alloc((size_t)2048 * 3072 * 2);
    float*   partB = (float*)alloc((size_t)4 * 2048 * 768 * 4);
    float2*  mlb   = (float2*)alloc((size_t)2 * 24 * 1024 * 8);

    transpose_cvt_kernel<<<dim3(24, 24, 12), 256, 0, stream>>>(wq_w,  wqkvaT, 768, 768,  0,   (size_t)1024 * 768);
    transpose_cvt_kernel<<<dim3(8,  24, 12), 256, 0, stream>>>(kva_w, wqkvaT, 768, 256,  768, (size_t)1024 * 768);
    transpose_cvt_kernel<<<dim3(48, 8,  12), 256, 0, stream>>>(kvb_w, kvbT,   256, 1536, 0,   (size_t)1536 * 256);
    transpose_cvt_kernel<<<dim3(24, 24, 12), 256, 0, stream>>>(out_w, outT,   768, 768,  0,   (size_t)768 * 768);
    transpose_cvt_kernel<<<dim3(96, 24, 12), 256, 0, stream>>>(fc_w,  fcT,    768, 3072, 0,   (size_t)3072 * 768);
    transpose_cvt_kernel<<<dim3(24, 96, 12), 256, 0, stream>>>(proj_w, projT, 3072, 768, 0,   (size_t)768 * 3072);
    cvt_wte_kernel<<<37824, 256, 0, stream>>>(wte, wteB);
    rope_tables_kernel<<<128, 256, 0, stream>>>(cosT, sinT);
    embed_kernel<<<6144, 256, 0, stream>>>(idxp, wte, wpe, x);
    ln_kernel<<<2048, 256, 0, stream>>>(x, ln1_w, ln1_b, h);  // ln1 of layer 0

    for (int l = 0; l < 12; ++l) {
        gemmT<64, 8, 256, true><<<dim3(32, 8), 256, 0, stream>>>(
            h, 768, wqkvaT + (size_t)l * 1024 * 768, 768,
            768, 768, 1024, wq_b + l * 768, kva_b + l * 256,
            qbuf, 768, lat, 256, 0, nullptr, nullptr, 0, 0, cosT, sinT);
        gemmT<64, 8, 256, true><<<dim3(32, 12), 256, 0, stream>>>(
            lat, 256, kvbT + (size_t)l * 1536 * 256, 256,
            256, 768, 1536, kvb_b + l * 1536, kvb_b + l * 1536 + 768,
            kvbuf, 768, vTb, 0, 1, nullptr, nullptr, 0, 0, cosT, sinT);
        attn_mfma<<<dim3(16, 24, 2), 256, 0, stream>>>(qbuf, kvbuf, vTb, partB, mlb);
        attn_merge<<<2048, 256, 0, stream>>>(partB, mlb, attnb);
        gemmT<64, 8, 256, false, true><<<dim3(32, 6, 2), 256, 0, stream>>>(
            attnb, 768, outT + (size_t)l * 768 * 768, 768,
            384, 768, 768, nullptr, nullptr,
            nullptr, 0, nullptr, 0, 0, nullptr, partB, 768, 0, nullptr, nullptr);
        reduce_ln_kernel<2><<<2048, 256, 0, stream>>>(
            x, partB, out_b + l * 768, ln2_w + l * 768, ln2_b + l * 768, h);
        gemm8<3, true, false><<<dim3(16, 16), 512, 0, stream>>>(
            h, 768, fcT + (size_t)l * 3072 * 768, 768,
            fc_b + l * 3072, fca, 3072, nullptr);
        gemm8<3, false, true><<<dim3(16, 4, 4), 512, 0, stream>>>(
            fca, 3072, projT + (size_t)l * 768 * 3072, 3072,
            nullptr, nullptr, 0, partB);
        const float* nw = (l < 11) ? ln1_w + (l + 1) * 768 : lnf_w;
        const float* nb = (l < 11) ? ln1_b + (l + 1) * 768 : lnf_b;
        reduce_ln_kernel<4><<<2048, 256, 0, stream>>>(
            x, partB, proj_b + l * 768, nw, nb, h);
    }
    lmhead8<<<dim3(8, 197), 512, 0, stream>>>(h, wteB, (float*)d_out);
}

// Round 17
// 1737.204 us; speedup vs baseline: 1.0122x; 1.0122x over previous
//
#include <hip/hip_runtime.h>
#include <cstdint>
#include <cstddef>

// GPT2-MLA forward, MI355X. Round 17: restore round-15 optimum (1738us; KV-split
// x2 from r16 measured +20us and is reverted). Final structure:
//  - weight prepass: vectorized transpose+cvt to bf16 [N][K] (BW-roofline)
//  - per layer: gemmT(qkva fused, RoPE fused) -> gemmT(kvb, RoPE+V^T fused) ->
//    attn_mfma (flash, online-softmax in regs, counted-vmcnt dbuf, defer-max) ->
//    gemmT out splitK2 -> reduce_ln -> gemm8 fc (4-phase 128x192, GELU) ->
//    gemm8 proj splitK4 -> reduce_ln(next ln1/lnf)
//  - lmhead8: 8-phase 256^2, counted vmcnt(4), XCD-chunked swizzle
// B=2,T=1024,D=768,L=12,H=12,HD=64,DL=256,V=50257 (wte padded to 50432=197*256)

typedef unsigned short ushortT;
typedef __bf16 bf16x8 __attribute__((ext_vector_type(8)));
typedef float f32x4 __attribute__((ext_vector_type(4)));

#define NHEAD 12
#define T_SEQ 1024

__device__ __forceinline__ float bf2f(unsigned short u) {
    union { unsigned int i; float f; } v; v.i = ((unsigned int)u) << 16; return v.f;
}
__device__ __forceinline__ unsigned short f2bf(float f) {
    union { float f; unsigned int i; } v; v.f = f;
    unsigned int r = v.i + 0x7fffu + ((v.i >> 16) & 1u);
    return (unsigned short)(r >> 16);
}
__device__ __forceinline__ unsigned int pack2(float a, float b) {
    return (unsigned int)f2bf(a) | ((unsigned int)f2bf(b) << 16);
}
__device__ __forceinline__ void gload_lds16(const void* g, void* l) {
    __builtin_amdgcn_global_load_lds((__attribute__((address_space(1))) void*)g,
                                     (__attribute__((address_space(3))) void*)l, 16, 0, 0);
}
template <int N>
__device__ __forceinline__ void wait_vmcnt() {
    if constexpr (N == 8)      asm volatile("s_waitcnt vmcnt(8)" ::: "memory");
    else if constexpr (N == 6) asm volatile("s_waitcnt vmcnt(6)" ::: "memory");
    else if constexpr (N == 5) asm volatile("s_waitcnt vmcnt(5)" ::: "memory");
    else if constexpr (N == 4) asm volatile("s_waitcnt vmcnt(4)" ::: "memory");
    else if constexpr (N == 3) asm volatile("s_waitcnt vmcnt(3)" ::: "memory");
    else                       asm volatile("s_waitcnt vmcnt(0)" ::: "memory");
}

// ---------------- weight convert / transpose (float4 / ushort4 vectorized) ----------------
__global__ __launch_bounds__(256) void transpose_cvt_kernel(
    const float* __restrict__ in, ushortT* __restrict__ outp,
    int K, int N, int outRowOff, size_t outLS) {
    __shared__ float tile[32][33];
    const int tid = threadIdx.x;
    const int n0 = blockIdx.x * 32, k0 = blockIdx.y * 32;
    const float* src = in + (size_t)blockIdx.z * K * N;
    {
        const int r = tid >> 3, cg = tid & 7;
        float4 v = *(const float4*)(src + (size_t)(k0 + r) * N + n0 + cg * 4);
        tile[r][cg * 4 + 0] = v.x; tile[r][cg * 4 + 1] = v.y;
        tile[r][cg * 4 + 2] = v.z; tile[r][cg * 4 + 3] = v.w;
    }
    __syncthreads();
    {
        const int nr = tid >> 3, kg = tid & 7;
        ushort4 o;
        o.x = f2bf(tile[kg * 4 + 0][nr]);
        o.y = f2bf(tile[kg * 4 + 1][nr]);
        o.z = f2bf(tile[kg * 4 + 2][nr]);
        o.w = f2bf(tile[kg * 4 + 3][nr]);
        ushortT* dst = outp + (size_t)blockIdx.z * outLS;
        *(ushort4*)(dst + (size_t)(outRowOff + n0 + nr) * K + k0 + kg * 4) = o;
    }
}

__global__ void cvt_wte_kernel(const float* __restrict__ in, ushortT* __restrict__ outp) {
    size_t i4 = (size_t)blockIdx.x * 256 + threadIdx.x;
    ushort4 o;
    if (i4 < 9649344) {
        float4 v = ((const float4*)in)[i4];
        o.x = f2bf(v.x); o.y = f2bf(v.y); o.z = f2bf(v.z); o.w = f2bf(v.w);
    } else { o.x = 0; o.y = 0; o.z = 0; o.w = 0; }
    ((ushort4*)outp)[i4] = o;
}

// ---------------- embedding ----------------
__global__ void embed_kernel(const int* __restrict__ idx, const float* __restrict__ wte,
                             const float* __restrict__ wpe, float* __restrict__ x) {
    int i = blockIdx.x * 256 + threadIdx.x;
    int row = i / 768, d = i - row * 768;
    int t = row & 1023;
    x[i] = wte[(size_t)idx[row] * 768 + d] + wpe[(size_t)t * 768 + d];
}

// ---------------- rope tables ----------------
__global__ void rope_tables_kernel(float* __restrict__ cosT, float* __restrict__ sinT) {
    int i = blockIdx.x * 256 + threadIdx.x;  // 1024*32
    int t = i >> 5, f = i & 31;
    float invf = exp2f(-(float)f * (13.287712379549449f / 32.0f));
    float ang = (float)t * invf;
    cosT[i] = cosf(ang);
    sinT[i] = sinf(ang);
}

// ---------------- layernorm (standalone; used once after embed) ----------------
__global__ __launch_bounds__(256) void ln_kernel(const float* __restrict__ x,
                                                 const float* __restrict__ wg,
                                                 const float* __restrict__ bg,
                                                 ushortT* __restrict__ outp) {
    const int row = blockIdx.x, tid = threadIdx.x;
    const float* xr = x + (size_t)row * 768;
    float v0 = xr[tid], v1 = xr[tid + 256], v2 = xr[tid + 512];
    float s = v0 + v1 + v2;
    float ss = v0 * v0 + v1 * v1 + v2 * v2;
#pragma unroll
    for (int off = 32; off >= 1; off >>= 1) {
        s += __shfl_xor(s, off);
        ss += __shfl_xor(ss, off);
    }
    __shared__ float sb[4], ssb[4];
    if ((tid & 63) == 0) { sb[tid >> 6] = s; ssb[tid >> 6] = ss; }
    __syncthreads();
    float S = sb[0] + sb[1] + sb[2] + sb[3];
    float SS = ssb[0] + ssb[1] + ssb[2] + ssb[3];
    const float mean = S * (1.0f / 768.0f);
    float var = SS * (1.0f / 768.0f) - mean * mean;
    const float rs = rsqrtf(var + 1e-5f);
    ushortT* orow = outp + (size_t)row * 768;
    orow[tid]       = f2bf((v0 - mean) * rs * wg[tid]       + bg[tid]);
    orow[tid + 256] = f2bf((v1 - mean) * rs * wg[tid + 256] + bg[tid + 256]);
    orow[tid + 512] = f2bf((v2 - mean) * rs * wg[tid + 512] + bg[tid + 512]);
}

// ---------------- fused split-K reduce + residual + LayerNorm ----------------
template <int NP>
__global__ __launch_bounds__(256) void reduce_ln_kernel(
    float* __restrict__ x, const float* __restrict__ part,
    const float* __restrict__ bias,
    const float* __restrict__ wg, const float* __restrict__ bg,
    ushortT* __restrict__ outp) {
    const int row = blockIdx.x, tid = threadIdx.x;
    const size_t base = (size_t)row * 768;
    float4 v = {0.f, 0.f, 0.f, 0.f};
    if (tid < 192) {
        v = *(const float4*)(x + base + tid * 4);
        const float4 b4 = *(const float4*)(bias + tid * 4);
        v.x += b4.x; v.y += b4.y; v.z += b4.z; v.w += b4.w;
#pragma unroll
        for (int p = 0; p < NP; ++p) {
            const float4 pv = *(const float4*)(part + (size_t)p * 1572864 + base + tid * 4);
            v.x += pv.x; v.y += pv.y; v.z += pv.z; v.w += pv.w;
        }
        *(float4*)(x + base + tid * 4) = v;
    }
    float s = v.x + v.y + v.z + v.w;
    float ss = v.x * v.x + v.y * v.y + v.z * v.z + v.w * v.w;
#pragma unroll
    for (int off = 32; off >= 1; off >>= 1) {
        s += __shfl_xor(s, off);
        ss += __shfl_xor(ss, off);
    }
    __shared__ float sb[4], ssb[4];
    if ((tid & 63) == 0) { sb[tid >> 6] = s; ssb[tid >> 6] = ss; }
    __syncthreads();
    const float S = sb[0] + sb[1] + sb[2] + sb[3];
    const float SS = ssb[0] + ssb[1] + ssb[2] + ssb[3];
    const float mean = S * (1.0f / 768.0f);
    const float var = SS * (1.0f / 768.0f) - mean * mean;
    const float rs = rsqrtf(var + 1e-5f);
    if (tid < 192) {
        const float4 w4 = *(const float4*)(wg + tid * 4);
        const float4 g4 = *(const float4*)(bg + tid * 4);
        ushort4 o;
        o.x = f2bf((v.x - mean) * rs * w4.x + g4.x);
        o.y = f2bf((v.y - mean) * rs * w4.y + g4.y);
        o.z = f2bf((v.z - mean) * rs * w4.z + g4.z);
        o.w = f2bf((v.w - mean) * rs * w4.w + g4.w);
        *(ushort4*)(outp + base + tid * 4) = o;
    }
}

// ---------------- generic GEMM (r8 skeleton) ----------------
template <int BM, int NF, int NTHR, bool ROPE, bool PARTIAL = false>
__global__ __launch_bounds__(NTHR) void gemmT(
    const ushortT* __restrict__ A, int lda,
    const ushortT* __restrict__ Bt, int ldb,
    int K, int CS, int Nstore,
    const float* __restrict__ bias0, const float* __restrict__ bias1,
    ushortT* __restrict__ outB0, int ld0,
    ushortT* __restrict__ outB1, int ld1, int mode1,
    const float* __restrict__ resid, float* __restrict__ outF, int ldF,
    int act, const float* __restrict__ cosT, const float* __restrict__ sinT) {
    constexpr int WC = (NTHR == 512) ? 4 : 2;
    constexpr int WMR = BM / 2;
    constexpr int MF = WMR / 16;
    constexpr int NFh = NF / WC;
    constexpr int WNh = NFh * 16;
    constexpr int ABYTES = BM * 128;
    constexpr int BBYTES = NF * 2048;
    constexpr int BUFB = ABYTES + BBYTES;
    constexpr int A_LOADS = (BM * 8) / NTHR;
    constexpr int B_LOADS = (NF * 128) / NTHR;
    constexpr int S = A_LOADS + B_LOADS;
    __shared__ __align__(16) char lds[2 * BUFB];
    const int tid = threadIdx.x;
    const int w = tid >> 6, lane = tid & 63;
    const int wm = w / WC, wn = w % WC;
    const int gx = gridDim.x;
    const int nwg = gx * gridDim.y;
    const int flat = blockIdx.x + gx * blockIdx.y;
    const int xcd = flat & 7, loc = flat >> 3;
    const int qq = nwg >> 3, rr_ = nwg & 7;
    const int swz = (xcd < rr_ ? xcd * (qq + 1) : rr_ * (qq + 1) + (xcd - rr_) * qq) + loc;
    const int m0 = (swz % gx) * BM, n0 = (swz / gx) * NF * 16;
    const int fr = lane & 15, kg = lane >> 4;
    const size_t ldaB = (size_t)lda * 2, ldbB = (size_t)ldb * 2;
    int koff = 0;
    if constexpr (PARTIAL) koff = blockIdx.z * K;
    const char* Ab = (const char*)A + (size_t)koff * 2;
    const char* Bb = (const char*)Bt + (size_t)koff * 2;
    float* outFz = outF;
    if constexpr (PARTIAL) outFz = outF + (size_t)blockIdx.z * 2048 * (size_t)ldF;
    f32x4 acc[MF][NFh] = {};

    auto stage = [&](int buf, int t) {
        const size_t ktB = (size_t)t << 7;
        char* As_ = lds + buf * BUFB;
        char* Bs_ = As_ + ABYTES;
#pragma unroll
        for (int jj = 0; jj < A_LOADS; ++jj) {
            const int i = tid + jj * NTHR;
            const int r = i >> 3, c = i & 7, cc = c ^ (r & 7);
            gload_lds16(Ab + (size_t)(m0 + r) * ldaB + ktB + cc * 16, As_ + i * 16);
        }
#pragma unroll
        for (int jj = 0; jj < B_LOADS; ++jj) {
            const int i = tid + jj * NTHR;
            const int r = i >> 3, c = i & 7, cc = c ^ (r & 7);
            gload_lds16(Bb + (size_t)(n0 + r) * ldbB + ktB + cc * 16, Bs_ + i * 16);
        }
    };

    const int nk = K >> 6;
    stage(0, 0);
    if (nk > 1) { stage(1, 1); wait_vmcnt<S>(); }
    else        { wait_vmcnt<0>(); }
    __builtin_amdgcn_s_barrier();

    for (int t = 0; t < nk; ++t) {
        const int cur = t & 1;
        const char* As_ = lds + cur * BUFB;
        const char* Bs_ = As_ + ABYTES;
        bf16x8 af[MF][2], bfr[NFh][2];
#pragma unroll
        for (int mf = 0; mf < MF; ++mf) {
            const int row = wm * WMR + mf * 16 + fr;
#pragma unroll
            for (int ks = 0; ks < 2; ++ks)
                af[mf][ks] = *(const bf16x8*)(As_ + row * 128 + (((ks * 4 + kg) ^ (row & 7)) << 4));
        }
#pragma unroll
        for (int nf = 0; nf < NFh; ++nf) {
            const int row = wn * WNh + nf * 16 + fr;
#pragma unroll
            for (int ks = 0; ks < 2; ++ks)
                bfr[nf][ks] = *(const bf16x8*)(Bs_ + row * 128 + (((ks * 4 + kg) ^ (row & 7)) << 4));
        }
        if (t + 2 < nk) {
            asm volatile("s_waitcnt lgkmcnt(0)" ::: "memory");
            __builtin_amdgcn_s_barrier();
            stage(cur, t + 2);
        }
#pragma unroll
        for (int ks = 0; ks < 2; ++ks)
#pragma unroll
            for (int nf = 0; nf < NFh; ++nf)
#pragma unroll
                for (int mf = 0; mf < MF; ++mf)
                    acc[mf][nf] = __builtin_amdgcn_mfma_f32_16x16x32_bf16(
                        af[mf][ks], bfr[nf][ks], acc[mf][nf], 0, 0, 0);
        if (t + 1 < nk) {
            if (t + 2 < nk) wait_vmcnt<S>();
            else            wait_vmcnt<0>();
            __builtin_amdgcn_s_barrier();
        }
    }

    if constexpr (ROPE) {
        float vv[MF][4][4];
#pragma unroll
        for (int mf = 0; mf < MF; ++mf)
#pragma unroll
            for (int nf = 0; nf < 4; ++nf) {
                const int gcol = n0 + wn * 64 + nf * 16 + fr;
                float bv = (gcol < CS) ? (bias0 ? bias0[gcol] : 0.0f)
                                       : (bias1 ? bias1[gcol - CS] : 0.0f);
#pragma unroll
                for (int j = 0; j < 4; ++j) vv[mf][nf][j] = acc[mf][nf][j] + bv;
            }
        if (n0 + wn * 64 < 768) {
#pragma unroll
            for (int mf = 0; mf < MF; ++mf)
#pragma unroll
                for (int j = 0; j < 4; ++j) {
                    const int grow = m0 + wm * WMR + mf * 16 + kg * 4 + j;
                    const int t = grow & 1023;
                    const float c0 = cosT[t * 32 + fr],      s0 = sinT[t * 32 + fr];
                    const float c1 = cosT[t * 32 + 16 + fr], s1 = sinT[t * 32 + 16 + fr];
                    float x1 = vv[mf][0][j], x2 = vv[mf][2][j];
                    vv[mf][0][j] = x1 * c0 - x2 * s0;
                    vv[mf][2][j] = x2 * c0 + x1 * s0;
                    float y1 = vv[mf][1][j], y2 = vv[mf][3][j];
                    vv[mf][1][j] = y1 * c1 - y2 * s1;
                    vv[mf][3][j] = y2 * c1 + y1 * s1;
                }
        }
#pragma unroll
        for (int mf = 0; mf < MF; ++mf)
#pragma unroll
            for (int nf = 0; nf < 4; ++nf) {
                const int gcol = n0 + wn * 64 + nf * 16 + fr;
                if (gcol >= Nstore) continue;
#pragma unroll
                for (int j = 0; j < 4; ++j) {
                    const int grow = m0 + wm * WMR + mf * 16 + kg * 4 + j;
                    const float v = vv[mf][nf][j];
                    if (gcol < CS) {
                        if (outB0) outB0[(size_t)grow * ld0 + gcol] = f2bf(v);
                    } else if (outB1) {
                        if (mode1 == 0) {
                            outB1[(size_t)grow * ld1 + gcol - CS] = f2bf(v);
                        } else {
                            const int bb = grow >> 10, tt = grow & 1023;
                            const int hd = gcol - CS;
                            outB1[((size_t)((bb * 12 + (hd >> 6)) * 64 + (hd & 63)) << 10) + tt] = f2bf(v);
                        }
                    }
                }
            }
    } else {
#pragma unroll
        for (int mf = 0; mf < MF; ++mf) {
#pragma unroll
            for (int nf = 0; nf < NFh; ++nf) {
                const int gcol = n0 + wn * WNh + nf * 16 + fr;
                if (gcol >= Nstore) continue;
                float bv = 0.0f;
                if (gcol < CS) { if (bias0) bv = bias0[gcol]; }
                else           { if (bias1) bv = bias1[gcol - CS]; }
#pragma unroll
                for (int j = 0; j < 4; ++j) {
                    const int grow = m0 + wm * WMR + mf * 16 + kg * 4 + j;
                    float v = acc[mf][nf][j] + bv;
                    if (resid) v += resid[(size_t)grow * ldF + gcol];
                    if (act) v = 0.5f * v * (1.0f + erff(v * 0.70710678118654752f));
                    if (outFz) outFz[(size_t)grow * ldF + gcol] = v;
                    if (gcol < CS) {
                        if (outB0) outB0[(size_t)grow * ld0 + gcol] = f2bf(v);
                    } else if (outB1) {
                        if (mode1 == 0) {
                            outB1[(size_t)grow * ld1 + gcol - CS] = f2bf(v);
                        } else {
                            const int bb = grow >> 10, tt = grow & 1023;
                            const int hd = gcol - CS;
                            outB1[((size_t)((bb * 12 + (hd >> 6)) * 64 + (hd & 63)) << 10) + tt] = f2bf(v);
                        }
                    }
                }
            }
        }
    }
}

// ---------------- 4-phase 128x(NFW*64) GEMM (fc / proj), K = 768 per slice ----
#define FC_PHASE(SLOT, MB, STAGE_STMT, TAILWAIT)                               \
    {                                                                          \
        bf16x8 af[2][2];                                                       \
        _Pragma("unroll") for (int m = 0; m < 2; ++m)                          \
        _Pragma("unroll") for (int ks = 0; ks < 2; ++ks) {                     \
            const int row = wm * 64 + (MB + m) * 16 + fr;                      \
            af[m][ks] = *(const bf16x8*)(lds + (SLOT) * 16384 + row * 128 +    \
                                         (((ks * 4 + kg) ^ (row & 7)) << 4));  \
        }                                                                      \
        STAGE_STMT;                                                            \
        __builtin_amdgcn_s_barrier();                                          \
        asm volatile("s_waitcnt lgkmcnt(0)" ::: "memory");                     \
        __builtin_amdgcn_sched_barrier(0);                                     \
        __builtin_amdgcn_s_setprio(1);                                         \
        _Pragma("unroll") for (int ks = 0; ks < 2; ++ks)                       \
        _Pragma("unroll") for (int nf = 0; nf < NFW; ++nf)                     \
        _Pragma("unroll") for (int m = 0; m < 2; ++m)                          \
            acc[MB + m][nf] = __builtin_amdgcn_mfma_f32_16x16x32_bf16(         \
                af[m][ks], bfr[nf][ks], acc[MB + m][nf], 0, 0, 0);             \
        __builtin_amdgcn_s_setprio(0);                                         \
        TAILWAIT;                                                              \
        __builtin_amdgcn_s_barrier();                                          \
    }

template <int NFW, bool GELU, bool PARTIAL>
__global__ __launch_bounds__(512, 1) void gemm8(
    const ushortT* __restrict__ A, int lda,
    const ushortT* __restrict__ Bt, int ldb,
    const float* __restrict__ bias,
    ushortT* __restrict__ outB, int ldo,
    float* __restrict__ outF) {
    constexpr int BSLOT = NFW * 8192;           // B bytes per slot
    __shared__ __align__(16) char lds[32768 + 2 * BSLOT];
    const int tid = threadIdx.x;
    const int w = tid >> 6, lane = tid & 63;
    const int wm = w >> 2, wn = w & 3;          // 2M x 4N waves
    const int fr = lane & 15, kg = lane >> 4;
    const int gx = gridDim.x;
    const int nwg = gx * gridDim.y;             // multiple of 8 for all users
    const int flat = blockIdx.x + gx * blockIdx.y;
    const int cpx = nwg >> 3;
    const int swz = (flat & 7) * cpx + (flat >> 3);
    const int m0 = (swz % gx) * 128, n0 = (swz / gx) * (NFW * 64);
    const size_t ldaB = (size_t)lda * 2, ldbB = (size_t)ldb * 2;
    int koff = 0;
    if constexpr (PARTIAL) koff = blockIdx.z * 768;
    const char* Ag = (const char*)A + (size_t)koff * 2;
    const char* Bg = (const char*)Bt + (size_t)koff * 2;
    float* outFz = nullptr;
    if constexpr (PARTIAL) outFz = outF + (size_t)blockIdx.z * 2048 * 768;

    auto stA = [&](int tile) {  // 2 loads/thread
        char* dst = lds + (tile & 1) * 16384;
#pragma unroll
        for (int jj = 0; jj < 2; ++jj) {
            const int i = tid + jj * 512;
            const int r = i >> 3, c = i & 7, cc = c ^ (r & 7);
            gload_lds16(Ag + (size_t)(m0 + r) * ldaB + tile * 128 + cc * 16, dst + i * 16);
        }
    };
    auto stB = [&](int tile) {  // NFW loads/thread
        char* dst = lds + 32768 + (tile & 1) * BSLOT;
#pragma unroll
        for (int jj = 0; jj < NFW; ++jj) {
            const int i = tid + jj * 512;
            const int r = i >> 3, c = i & 7, cc = c ^ (r & 7);
            gload_lds16(Bg + (size_t)(n0 + r) * ldbB + tile * 128 + cc * 16, dst + i * 16);
        }
    };

    f32x4 acc[4][NFW] = {};
    // prologue: A(0), B(0), B(1); wait leaves B(1)'s NFW loads in flight
    stA(0); stB(0); stB(1);
    wait_vmcnt<NFW>();
    __builtin_amdgcn_s_barrier();

    const int browB = wn * (NFW * 16);
    for (int i = 0; i < 6; ++i) {  // 12 K-tiles of 64, 2 per iter
        const int t1 = 2 * i + 1;
        const bool st = (i < 5);
        bf16x8 bfr[NFW][2];
#pragma unroll
        for (int nf = 0; nf < NFW; ++nf)
#pragma unroll
            for (int ks = 0; ks < 2; ++ks) {
                const int row = browB + nf * 16 + fr;
                bfr[nf][ks] = *(const bf16x8*)(lds + 32768 + 0 * BSLOT + row * 128 +
                                               (((ks * 4 + kg) ^ (row & 7)) << 4));
            }
        FC_PHASE(0, 0, stA(t1), )
        FC_PHASE(0, 2, if (st) stB(t1 + 1),
                 if (st) { wait_vmcnt<NFW>(); } else { wait_vmcnt<0>(); }
                 __builtin_amdgcn_sched_barrier(0))
#pragma unroll
        for (int nf = 0; nf < NFW; ++nf)
#pragma unroll
            for (int ks = 0; ks < 2; ++ks) {
                const int row = browB + nf * 16 + fr;
                bfr[nf][ks] = *(const bf16x8*)(lds + 32768 + 1 * BSLOT + row * 128 +
                                               (((ks * 4 + kg) ^ (row & 7)) << 4));
            }
        FC_PHASE(1, 0, if (st) stA(t1 + 1), )
        FC_PHASE(1, 2, if (st) stB(t1 + 2),
                 if (st) { wait_vmcnt<NFW>(); } else { wait_vmcnt<0>(); }
                 __builtin_amdgcn_sched_barrier(0))
    }

    // epilogue
#pragma unroll
    for (int mf = 0; mf < 4; ++mf)
#pragma unroll
        for (int nf = 0; nf < NFW; ++nf) {
            const int col = n0 + wn * (NFW * 16) + nf * 16 + fr;
#pragma unroll
            for (int j = 0; j < 4; ++j) {
                const int row = m0 + wm * 64 + mf * 16 + kg * 4 + j;
                if constexpr (PARTIAL) {
                    outFz[(size_t)row * 768 + col] = acc[mf][nf][j];
                } else {
                    float v = acc[mf][nf][j] + bias[col];
                    if constexpr (GELU)
                        v = 0.5f * v * (1.0f + erff(v * 0.70710678118654752f));
                    outB[(size_t)row * ldo + col] = f2bf(v);
                }
            }
        }
}

// ---------------- 8-phase 256x256 lm_head ----------
#define LM_PHASE(SLOT, MB, STAGE_STMT, TAILWAIT)                              \
    {                                                                          \
        bf16x8 af[2][2];                                                       \
        _Pragma("unroll") for (int m = 0; m < 2; ++m)                          \
        _Pragma("unroll") for (int ks = 0; ks < 2; ++ks) {                     \
            const int row = (MB + m) * 16 + fr;                                \
            af[m][ks] = *(const bf16x8*)(Aw + (SLOT) * 32768 + row * 128 +     \
                                         (((ks * 4 + kg) ^ (row & 7)) << 4));  \
        }                                                                      \
        STAGE_STMT;                                                            \
        __builtin_amdgcn_s_barrier();                                          \
        asm volatile("s_waitcnt lgkmcnt(0)" ::: "memory");                     \
        __builtin_amdgcn_sched_barrier(0);                                     \
        __builtin_amdgcn_s_setprio(1);                                         \
        _Pragma("unroll") for (int ks = 0; ks < 2; ++ks)                       \
        _Pragma("unroll") for (int nf = 0; nf < 4; ++nf)                       \
        _Pragma("unroll") for (int m = 0; m < 2; ++m)                          \
            acc[MB + m][nf] = __builtin_amdgcn_mfma_f32_16x16x32_bf16(         \
                af[m][ks], bfr[nf][ks], acc[MB + m][nf], 0, 0, 0);             \
        __builtin_amdgcn_s_setprio(0);                                         \
        TAILWAIT;                                                              \
        __builtin_amdgcn_s_barrier();                                          \
    }

__global__ __launch_bounds__(512, 1) void lmhead8(
    const ushortT* __restrict__ A, const ushortT* __restrict__ Bt,
    float* __restrict__ outF) {
    __shared__ __align__(16) char lds[131072];
    const int tid = threadIdx.x;
    const int w = tid >> 6, lane = tid & 63;
    const int wm = w >> 2, wn = w & 3;
    const int fr = lane & 15, kg = lane >> 4;
    const int flat = blockIdx.x + 8 * blockIdx.y;
    const int swz = (flat & 7) * 197 + (flat >> 3);
    const int m0 = (swz & 7) * 256, n0 = (swz >> 3) * 256;

    const char* Ag = (const char*)A;
    const char* Bg = (const char*)Bt;
    const char* Aw = lds + wm * 16384;
    const char* Bw = lds + 65536 + (wn >> 1) * 16384;
    const int brow0 = (wn & 1) * 64;

    auto stA = [&](int tile, int half) {
        char* dst = lds + (tile & 1) * 32768 + half * 16384;
#pragma unroll
        for (int jj = 0; jj < 2; ++jj) {
            const int i = tid + jj * 512;
            const int r = i >> 3, c = i & 7, cc = c ^ (r & 7);
            gload_lds16(Ag + (size_t)(m0 + half * 128 + r) * 1536 + tile * 128 + cc * 16,
                        dst + i * 16);
        }
    };
    auto stB = [&](int tile, int half) {
        char* dst = lds + 65536 + (tile & 1) * 32768 + half * 16384;
#pragma unroll
        for (int jj = 0; jj < 2; ++jj) {
            const int i = tid + jj * 512;
            const int r = i >> 3, c = i & 7, cc = c ^ (r & 7);
            gload_lds16(Bg + (size_t)(n0 + half * 128 + r) * 1536 + tile * 128 + cc * 16,
                        dst + i * 16);
        }
    };

    f32x4 acc[8][4] = {};
    stA(0, 0); stA(0, 1); stB(0, 0); stB(0, 1); stB(1, 0); stB(1, 1);
    wait_vmcnt<4>();
    __builtin_amdgcn_s_barrier();

    for (int i = 0; i < 6; ++i) {
        const int t1 = 2 * i + 1;
        const bool st = (i < 5);
        bf16x8 bfr[4][2];
#pragma unroll
        for (int nf = 0; nf < 4; ++nf)
#pragma unroll
            for (int ks = 0; ks < 2; ++ks) {
                const int row = brow0 + nf * 16 + fr;
                bfr[nf][ks] = *(const bf16x8*)(Bw + 0 * 32768 + row * 128 +
                                               (((ks * 4 + kg) ^ (row & 7)) << 4));
            }
        LM_PHASE(0, 0, stA(t1, 0), )
        LM_PHASE(0, 2, stA(t1, 1), )
        LM_PHASE(0, 4, if (st) stB(t1 + 1, 0), )
        LM_PHASE(0, 6, if (st) stB(t1 + 1, 1),
                 if (st) { wait_vmcnt<4>(); } else { wait_vmcnt<0>(); }
                 __builtin_amdgcn_sched_barrier(0))
#pragma unroll
        for (int nf = 0; nf < 4; ++nf)
#pragma unroll
            for (int ks = 0; ks < 2; ++ks) {
                const int row = brow0 + nf * 16 + fr;
                bfr[nf][ks] = *(const bf16x8*)(Bw + 1 * 32768 + row * 128 +
                                               (((ks * 4 + kg) ^ (row & 7)) << 4));
            }
        LM_PHASE(1, 0, if (st) stA(t1 + 1, 0), )
        LM_PHASE(1, 2, if (st) stA(t1 + 1, 1), )
        LM_PHASE(1, 4, if (st) stB(t1 + 2, 0), )
        LM_PHASE(1, 6, if (st) stB(t1 + 2, 1),
                 if (st) { wait_vmcnt<4>(); } else { wait_vmcnt<0>(); }
                 __builtin_amdgcn_sched_barrier(0))
    }

#pragma unroll
    for (int mf = 0; mf < 8; ++mf)
#pragma unroll
        for (int nf = 0; nf < 4; ++nf) {
            const int col = n0 + wn * 64 + nf * 16 + fr;
            if (col < 50257) {
#pragma unroll
                for (int j = 0; j < 4; ++j) {
                    const int row = m0 + wm * 128 + mf * 16 + kg * 4 + j;
                    outF[(size_t)row * 50257 + col] = acc[mf][nf][j];
                }
            }
        }
}

// ---------------- MFMA flash attention (r12 form) ----------------
__global__ __launch_bounds__(256) void attn_mfma(const ushortT* __restrict__ q,
                                                 const ushortT* __restrict__ kbuf,
                                                 const ushortT* __restrict__ vT,
                                                 ushortT* __restrict__ attnb) {
    __shared__ __align__(16) char lds[41472];
    const int tid = threadIdx.x, w = tid >> 6, lane = tid & 63;
    const int fr = lane & 15, kg = lane >> 4;
    const int flat = blockIdx.x + 16 * blockIdx.y;
    const int nf2 = (flat & 7) * 48 + (flat >> 3);
    const int bh = nf2 >> 4;
    const int b = bh / NHEAD, h = bh % NHEAD;
    const int qb = (15 - (nf2 & 15)) * 64;
    const int q0 = qb + w * 16;
    const int nst = (qb >> 6) + 1, diag = qb >> 6;

    const ushortT* qrow = q + ((size_t)(b * 1024 + q0 + fr) * 768 + h * 64);
    const bf16x8 qf0 = *(const bf16x8*)(qrow + kg * 8);
    const bf16x8 qf1 = *(const bf16x8*)(qrow + 32 + kg * 8);

    const char* kgb = (const char*)kbuf + ((size_t)(b * 1024) * 768 + h * 64) * 2;
    const char* vgb = (const char*)vT + ((size_t)(b * 12 + h) * 65536) * 2;
    char* Pw = lds + 32768 + w * 2176 + fr * 136;

    auto stage = [&](int buf, int st) {
#pragma unroll
        for (int jj = 0; jj < 2; ++jj) {
            const int i = tid + jj * 256;
            const int r = i >> 3, c = i & 7, cc = c ^ (r & 7);
            gload_lds16(kgb + (size_t)(st * 64 + r) * 1536 + cc * 16, lds + buf * 8192 + i * 16);
            gload_lds16(vgb + (size_t)r * 2048 + st * 128 + cc * 16, lds + 16384 + buf * 8192 + i * 16);
        }
    };

    float m_r = -1e30f, l_r = 0.0f;
    f32x4 o[4] = {};

    stage(0, 0);
    if (nst > 1) stage(1, 1);
    for (int st = 0; st < nst; ++st) {
        const int cur = st & 1;
        if (st + 1 < nst) wait_vmcnt<4>();
        else              wait_vmcnt<0>();
        __builtin_amdgcn_s_barrier();
        const char* Kd = lds + cur * 8192;
        const char* Vd = lds + 16384 + cur * 8192;

        f32x4 sfr[4];
        __builtin_amdgcn_s_setprio(1);
#pragma unroll
        for (int n = 0; n < 4; ++n) {
            const int row = n * 16 + fr;
            bf16x8 k0 = *(const bf16x8*)(Kd + row * 128 + ((kg ^ (row & 7)) << 4));
            bf16x8 k1 = *(const bf16x8*)(Kd + row * 128 + (((4 + kg) ^ (row & 7)) << 4));
            f32x4 sa = {0.0f, 0.0f, 0.0f, 0.0f};
            sa = __builtin_amdgcn_mfma_f32_16x16x32_bf16(k0, qf0, sa, 0, 0, 0);
            sa = __builtin_amdgcn_mfma_f32_16x16x32_bf16(k1, qf1, sa, 0, 0, 0);
            sfr[n] = sa;
        }
        __builtin_amdgcn_s_setprio(0);
        const int qoff = w * 16 + fr;
#pragma unroll
        for (int n = 0; n < 4; ++n)
#pragma unroll
            for (int j = 0; j < 4; ++j) {
                float v = sfr[n][j] * 0.125f;
                if (st == diag && (n * 16 + kg * 4 + j) > qoff) v = -1e30f;
                sfr[n][j] = v;
            }
        float tm = -1e30f;
#pragma unroll
        for (int n = 0; n < 4; ++n)
#pragma unroll
            for (int j = 0; j < 4; ++j) tm = fmaxf(tm, sfr[n][j]);
        tm = fmaxf(tm, __shfl_xor(tm, 16));
        tm = fmaxf(tm, __shfl_xor(tm, 32));
        // defer-max (T13): keep old running max when growth <= 8; P bounded by e^8
        if (!__all(tm <= m_r + 8.0f)) {
            const float mnew = fmaxf(m_r, tm);
            const float fac = __expf(m_r - mnew);
            m_r = mnew;
            l_r *= fac;
            const float ff0 = __shfl(fac, kg * 4 + 0);
            const float ff1 = __shfl(fac, kg * 4 + 1);
            const float ff2 = __shfl(fac, kg * 4 + 2);
            const float ff3 = __shfl(fac, kg * 4 + 3);
#pragma unroll
            for (int nf = 0; nf < 4; ++nf) {
                o[nf][0] *= ff0; o[nf][1] *= ff1; o[nf][2] *= ff2; o[nf][3] *= ff3;
            }
        }
#pragma unroll
        for (int n = 0; n < 4; ++n) {
            float e0 = __expf(sfr[n][0] - m_r);
            float e1 = __expf(sfr[n][1] - m_r);
            float e2 = __expf(sfr[n][2] - m_r);
            float e3 = __expf(sfr[n][3] - m_r);
            l_r += (e0 + e1) + (e2 + e3);
            uint2 pv;
            pv.x = pack2(e0, e1);
            pv.y = pack2(e2, e3);
            *(uint2*)(Pw + n * 32 + kg * 8) = pv;
        }
        __builtin_amdgcn_s_setprio(1);
#pragma unroll
        for (int ks = 0; ks < 2; ++ks) {
            uint2 a0 = *(const uint2*)(Pw + ks * 64 + kg * 16);
            uint2 a1 = *(const uint2*)(Pw + ks * 64 + kg * 16 + 8);
            union { uint4 u; bf16x8 v; } pa;
            pa.u = make_uint4(a0.x, a0.y, a1.x, a1.y);
#pragma unroll
            for (int nf = 0; nf < 4; ++nf) {
                const int row = nf * 16 + fr;
                bf16x8 vf = *(const bf16x8*)(Vd + row * 128 + (((ks * 4 + kg) ^ (row & 7)) << 4));
                o[nf] = __builtin_amdgcn_mfma_f32_16x16x32_bf16(pa.v, vf, o[nf], 0, 0, 0);
            }
        }
        __builtin_amdgcn_s_setprio(0);
        __builtin_amdgcn_s_barrier();
        if (st + 2 < nst) stage(cur, st + 2);
    }

    l_r += __shfl_xor(l_r, 16);
    l_r += __shfl_xor(l_r, 32);
    const float inv = 1.0f / l_r;
    const float iv0 = __shfl(inv, kg * 4 + 0);
    const float iv1 = __shfl(inv, kg * 4 + 1);
    const float iv2 = __shfl(inv, kg * 4 + 2);
    const float iv3 = __shfl(inv, kg * 4 + 3);
#pragma unroll
    for (int nf = 0; nf < 4; ++nf) {
        const size_t base = (size_t)(b * 1024 + q0) * 768 + h * 64 + nf * 16 + fr;
        attnb[base + (size_t)(kg * 4 + 0) * 768] = f2bf(o[nf][0] * iv0);
        attnb[base + (size_t)(kg * 4 + 1) * 768] = f2bf(o[nf][1] * iv1);
        attnb[base + (size_t)(kg * 4 + 2) * 768] = f2bf(o[nf][2] * iv2);
        attnb[base + (size_t)(kg * 4 + 3) * 768] = f2bf(o[nf][3] * iv3);
    }
}

// ---------------- host ----------------
extern "C" void kernel_launch(void* const* d_in, const int* in_sizes, int n_in,
                              void* d_out, int out_size, void* d_ws, size_t ws_size,
                              hipStream_t stream) {
    (void)in_sizes; (void)n_in; (void)out_size; (void)ws_size;
    const int*   idxp   = (const int*)d_in[0];
    const float* wte    = (const float*)d_in[1];
    const float* wpe    = (const float*)d_in[2];
    const float* ln1_w  = (const float*)d_in[3];
    const float* ln1_b  = (const float*)d_in[4];
    const float* wq_w   = (const float*)d_in[5];
    const float* wq_b   = (const float*)d_in[6];
    const float* kva_w  = (const float*)d_in[7];
    const float* kva_b  = (const float*)d_in[8];
    const float* kvb_w  = (const float*)d_in[9];
    const float* kvb_b  = (const float*)d_in[10];
    const float* out_w  = (const float*)d_in[11];
    const float* out_b  = (const float*)d_in[12];
    const float* ln2_w  = (const float*)d_in[13];
    const float* ln2_b  = (const float*)d_in[14];
    const float* fc_w   = (const float*)d_in[15];
    const float* fc_b   = (const float*)d_in[16];
    const float* proj_w = (const float*)d_in[17];
    const float* proj_b = (const float*)d_in[18];
    const float* lnf_w  = (const float*)d_in[19];
    const float* lnf_b  = (const float*)d_in[20];

    char* ws = (char*)d_ws;
    size_t off = 0;
    auto alloc = [&](size_t bytes) -> char* {
        char* p = ws + off;
        off += (bytes + 255) & ~(size_t)255;
        return p;
    };
    ushortT* wqkvaT = (ushortT*)alloc((size_t)12 * 1024 * 768 * 2);
    ushortT* kvbT   = (ushortT*)alloc((size_t)12 * 1536 * 256 * 2);
    ushortT* outT   = (ushortT*)alloc((size_t)12 * 768 * 768 * 2);
    ushortT* fcT    = (ushortT*)alloc((size_t)12 * 3072 * 768 * 2);
    ushortT* projT  = (ushortT*)alloc((size_t)12 * 768 * 3072 * 2);
    ushortT* wteB   = (ushortT*)alloc((size_t)50432 * 768 * 2);
    float* cosT = (float*)alloc((size_t)1024 * 32 * 4);
    float* sinT = (float*)alloc((size_t)1024 * 32 * 4);
    float*   x     = (float*)alloc((size_t)2048 * 768 * 4);
    ushortT* h     = (ushortT*)alloc((size_t)2048 * 768 * 2);
    ushortT* qbuf  = (ushortT*)alloc((size_t)2048 * 768 * 2);
    ushortT* lat   = (ushortT*)alloc((size_t)2048 * 256 * 2);
    ushortT* kvbuf = (ushortT*)alloc((size_t)2048 * 768 * 2);
    ushortT* vTb   = (ushortT*)alloc((size_t)24 * 64 * 1024 * 2);
    ushortT* attnb = (ushortT*)alloc((size_t)2048 * 768 * 2);
    ushortT* fca   = (ushortT*)alloc((size_t)2048 * 3072 * 2);
    float*   partB = (float*)alloc((size_t)4 * 2048 * 768 * 4);

    transpose_cvt_kernel<<<dim3(24, 24, 12), 256, 0, stream>>>(wq_w,  wqkvaT, 768, 768,  0,   (size_t)1024 * 768);
    transpose_cvt_kernel<<<dim3(8,  24, 12), 256, 0, stream>>>(kva_w, wqkvaT, 768, 256,  768, (size_t)1024 * 768);
    transpose_cvt_kernel<<<dim3(48, 8,  12), 256, 0, stream>>>(kvb_w, kvbT,   256, 1536, 0,   (size_t)1536 * 256);
    transpose_cvt_kernel<<<dim3(24, 24, 12), 256, 0, stream>>>(out_w, outT,   768, 768,  0,   (size_t)768 * 768);
    transpose_cvt_kernel<<<dim3(96, 24, 12), 256, 0, stream>>>(fc_w,  fcT,    768, 3072, 0,   (size_t)3072 * 768);
    transpose_cvt_kernel<<<dim3(24, 96, 12), 256, 0, stream>>>(proj_w, projT, 3072, 768, 0,   (size_t)768 * 3072);
    cvt_wte_kernel<<<37824, 256, 0, stream>>>(wte, wteB);
    rope_tables_kernel<<<128, 256, 0, stream>>>(cosT, sinT);
    embed_kernel<<<6144, 256, 0, stream>>>(idxp, wte, wpe, x);
    ln_kernel<<<2048, 256, 0, stream>>>(x, ln1_w, ln1_b, h);  // ln1 of layer 0

    for (int l = 0; l < 12; ++l) {
        gemmT<64, 8, 256, true><<<dim3(32, 8), 256, 0, stream>>>(
            h, 768, wqkvaT + (size_t)l * 1024 * 768, 768,
            768, 768, 1024, wq_b + l * 768, kva_b + l * 256,
            qbuf, 768, lat, 256, 0, nullptr, nullptr, 0, 0, cosT, sinT);
        gemmT<64, 8, 256, true><<<dim3(32, 12), 256, 0, stream>>>(
            lat, 256, kvbT + (size_t)l * 1536 * 256, 256,
            256, 768, 1536, kvb_b + l * 1536, kvb_b + l * 1536 + 768,
            kvbuf, 768, vTb, 0, 1, nullptr, nullptr, 0, 0, cosT, sinT);
        attn_mfma<<<dim3(16, 24), 256, 0, stream>>>(qbuf, kvbuf, vTb, attnb);
        gemmT<64, 8, 256, false, true><<<dim3(32, 6, 2), 256, 0, stream>>>(
            attnb, 768, outT + (size_t)l * 768 * 768, 768,
            384, 768, 768, nullptr, nullptr,
            nullptr, 0, nullptr, 0, 0, nullptr, partB, 768, 0, nullptr, nullptr);
        reduce_ln_kernel<2><<<2048, 256, 0, stream>>>(
            x, partB, out_b + l * 768, ln2_w + l * 768, ln2_b + l * 768, h);
        gemm8<3, true, false><<<dim3(16, 16), 512, 0, stream>>>(
            h, 768, fcT + (size_t)l * 3072 * 768, 768,
            fc_b + l * 3072, fca, 3072, nullptr);
        gemm8<3, false, true><<<dim3(16, 4, 4), 512, 0, stream>>>(
            fca, 3072, projT + (size_t)l * 768 * 3072, 3072,
            nullptr, nullptr, 0, partB);
        const float* nw = (l < 11) ? ln1_w + (l + 1) * 768 : lnf_w;
        const float* nb = (l < 11) ? ln1_b + (l + 1) * 768 : lnf_b;
        reduce_ln_kernel<4><<<2048, 256, 0, stream>>>(
            x, partB, proj_b + l * 768, nw, nb, h);
    }
    lmhead8<<<dim3(8, 197), 512, 0, stream>>>(h, wteB, (float*)d_out);
}